// Round 10
// baseline (420.325 us; speedup 1.0000x reference)
//
#include <hip/hip_runtime.h>
#include <hip/hip_bf16.h>
#include <math.h>

#define Bdim 16
#define Tdim 200
#define Pdim 100
#define EMB  100
#define Ddim 300
#define SKILL 30
#define Qdim 50
#define OUTD 50

// d_out layout (floats), concatenated in reference return order:
// res [B,T,50], res2 [B,T,30], kc_mask [B,T,30], attn [B,T,P,1]
#define OFF_RES   0
#define OFF_RES2  (Bdim*Tdim*OUTD)              // 160000
#define OFF_KC    (OFF_RES2 + Bdim*Tdim*SKILL)  // 256000
#define OFF_ATTN  (OFF_KC + Bdim*Tdim*SKILL)    // 352000

typedef __bf16 bf16x8 __attribute__((ext_vector_type(8)));
typedef __bf16 bf16x4 __attribute__((ext_vector_type(4)));
typedef float  f32x4  __attribute__((ext_vector_type(4)));

// MFMA geometry for the score GEMM
#define BM    128          // rows per block
#define KPAD  320          // padded K of wbt rows
#define WROWS 352          // wbt rows: 0..319 = W_trans^T cols, 320..351 = Wsk^T
#define ASTR  312          // A row stride in bf16 (624 B)
#define TPB   512          // 8 waves

#define ESW   32           // ES row width (30 skills padded to 32 fp32)

#define NROWS (Bdim*Tdim*Pdim)                  // 320000
#define WBT_BYTES ((size_t)WROWS*KPAD*2)        // 225280
#define ES_BYTES  ((size_t)NROWS*ESW*4)         // 40,960,000

__device__ __forceinline__ float fast_tanh(float x) {
    float t = __expf(2.0f * x);
    return 1.0f - 2.0f * __builtin_amdgcn_rcpf(t + 1.0f);
}
__device__ __forceinline__ float sigmoidf_(float z) {
    return 1.f / (1.f + expf(-z));
}

// ---------------------------------------------------------------------------
// Prep: build bf16 B matrix wbt[j][k] (stride KPAD):
//   rows j=0..319   : W_trans^T  (wbt[j][k] = Wt[k][j]), zeros outside 300
//   rows j=320..351 : Wsk^T      (wbt[320+s][k] = Wsk[k][s]), zeros outside
// The k-pad zeros make A-side pad/garbage reads harmless in the GEMM.
// ---------------------------------------------------------------------------
__global__ __launch_bounds__(256) void prep_wbt_kernel(
    const float* __restrict__ Wt, const float* __restrict__ Wsk,
    __bf16* __restrict__ wbt)
{
    int id = blockIdx.x * 256 + threadIdx.x;
    if (id >= WROWS * KPAD) return;
    int j = id / KPAD, k = id - j * KPAD;
    float v = 0.0f;
    if (j < KPAD) {
        if (j < Ddim && k < Ddim) v = Wt[k * Ddim + j];
    } else {
        int s = j - KPAD;
        if (s < SKILL && k < Ddim) v = Wsk[k * SKILL + s];
    }
    wbt[id] = (__bf16)v;
}

// ---------------------------------------------------------------------------
// Kernel A (MFMA): raw attention scores + optional ES = E @ W_skill spill.
// score[m] = tanh(E[m] @ W_trans + b_trans) @ W_att + b_att
// ES[m][s] = E[m] . Wsk[:,s]   (fp32, row stride 32; 41 MB total)
// Structure: no B_lds (B fragments straight from L2-resident wbt),
// barrier-free K-loop, 80 KB LDS -> 2 blocks/CU, VALU-lean gather.
// Waves wn<2 carry the 4 extra ES fragments (cols wn*16..wn*16+15).
// ---------------------------------------------------------------------------
template <bool WRITE_ES>
__global__ __launch_bounds__(TPB, 4) void score_mfma_kernel(
    const int*    __restrict__ c2v,
    const float*  __restrict__ en,
    const float*  __restrict__ ep,
    const __bf16* __restrict__ wbt,
    const float*  __restrict__ bt,
    const float*  __restrict__ wa,
    const float*  __restrict__ ba,
    float* __restrict__ scores,
    float* __restrict__ es_out)
{
    __shared__ __align__(16) __bf16 A_lds[BM * ASTR];   // 79872 B
    __shared__ __align__(16) char   aux_lds[2048];      // idx (early) / red (late)
    int*  idx_lds = (int*)aux_lds;                      // [BM*3] = 1536 B
    float (*red_lds)[BM] = (float (*)[BM])aux_lds;      // [4][BM] = 2048 B

    const int tid = threadIdx.x;
    const int m0  = blockIdx.x * BM;

    if (tid < BM * 3) idx_lds[tid] = c2v[(size_t)m0 * 3 + tid];
    __syncthreads();

    // ---- gather fp32 embeddings -> bf16 A tile (VALU-lean) ----
    {
        const int r   = tid >> 2;        // 0..127: one row per 4 threads
        const int sub = tid & 3;         // quarter of the row
        const int i0 = idx_lds[r * 3 + 0];
        const int i1 = idx_lds[r * 3 + 1];
        const int i2 = idx_lds[r * 3 + 2];
        __bf16* arow = &A_lds[r * ASTR];
        const float* srcs[3] = { en + (size_t)i0 * EMB,     // cols   0- 99
                                 en + (size_t)i2 * EMB,     // cols 100-199
                                 ep + (size_t)i1 * EMB };   // cols 200-299
        #pragma unroll
        for (int seg = 0; seg < 3; ++seg) {
            const float* src = srcs[seg];
            float4 v[7];
            #pragma unroll
            for (int k = 0; k < 7; ++k) {
                int j = sub + 4 * k;
                if (j < 25) v[k] = *(const float4*)(src + j * 4);
            }
            #pragma unroll
            for (int k = 0; k < 7; ++k) {
                int j = sub + 4 * k;
                if (j < 25) {
                    float4 w = v[k];
                    bf16x4 b4 = { (__bf16)w.x, (__bf16)w.y, (__bf16)w.z, (__bf16)w.w };
                    *(bf16x4*)(arow + seg * 100 + j * 4) = b4;
                }
            }
        }
        // zero pad cols 300..311 (NaN hygiene for the K-loop's last tile)
        if (sub < 3) *(bf16x4*)(arow + 300 + sub * 4) = (bf16x4){};
    }
    __syncthreads();

    const int wid = tid >> 6, lane = tid & 63;
    const int wm = wid >> 2, wn = wid & 3;       // 2 x 4 wave grid
    const int lr = lane & 15, lg = lane >> 4;
    const bool do_es = WRITE_ES && (wn < 2);

    f32x4 acc[4][5];
    f32x4 acc_es[4];
    #pragma unroll
    for (int mf = 0; mf < 4; ++mf) {
        #pragma unroll
        for (int nf = 0; nf < 5; ++nf) acc[mf][nf] = (f32x4){0.f, 0.f, 0.f, 0.f};
        acc_es[mf] = (f32x4){0.f, 0.f, 0.f, 0.f};
    }

    // ---- barrier-free K-loop: A from LDS, B fragments straight from L2 ----
    #pragma unroll
    for (int kt = 0; kt < 10; ++kt) {
        const int k0 = kt * 32;
        bf16x8 bfr[5];
        #pragma unroll
        for (int nf = 0; nf < 5; ++nf)
            bfr[nf] = *(const bf16x8*)&wbt[(size_t)(wn * 80 + nf * 16 + lr) * KPAD + k0 + lg * 8];
        bf16x8 af[4];
        #pragma unroll
        for (int mf = 0; mf < 4; ++mf) {
            bf16x8 a = *(const bf16x8*)&A_lds[(wm * 64 + mf * 16 + lr) * ASTR + k0 + lg * 8];
            if (kt == 9 && lg == 3) a = (bf16x8){};   // cols 312..319: out of row
            af[mf] = a;
        }
        #pragma unroll
        for (int mf = 0; mf < 4; ++mf)
            #pragma unroll
            for (int nf = 0; nf < 5; ++nf)
                acc[mf][nf] = __builtin_amdgcn_mfma_f32_16x16x32_bf16(
                    af[mf], bfr[nf], acc[mf][nf], 0, 0, 0);
        if (do_es) {
            bf16x8 bes = *(const bf16x8*)&wbt[(size_t)(KPAD + wn * 16 + lr) * KPAD + k0 + lg * 8];
            #pragma unroll
            for (int mf = 0; mf < 4; ++mf)
                acc_es[mf] = __builtin_amdgcn_mfma_f32_16x16x32_bf16(
                    af[mf], bes, acc_es[mf], 0, 0, 0);
        }
    }

    // ---- ES spill: fp32, row stride 32 (fire-and-forget) ----
    if (do_es) {
        #pragma unroll
        for (int mf = 0; mf < 4; ++mf)
            #pragma unroll
            for (int i = 0; i < 4; ++i) {
                int row = wm * 64 + mf * 16 + lg * 4 + i;
                int col = wn * 16 + lr;
                es_out[(size_t)(m0 + row) * ESW + col] = acc_es[mf][i];
            }
    }

    // ---- epilogue: tanh * W_att, reduce over columns ----
    float btv[5], wav[5];
    #pragma unroll
    for (int nf = 0; nf < 5; ++nf) {
        int c = wn * 80 + nf * 16 + lr;
        bool ok = (c < Ddim);
        btv[nf] = ok ? bt[c] : 0.f;
        wav[nf] = ok ? wa[c] : 0.f;
    }
    float sred[4][4];
    #pragma unroll
    for (int mf = 0; mf < 4; ++mf) {
        #pragma unroll
        for (int i = 0; i < 4; ++i) {
            float s = 0.f;
            #pragma unroll
            for (int nf = 0; nf < 5; ++nf)
                s += fast_tanh(acc[mf][nf][i] + btv[nf]) * wav[nf];
            s += __shfl_xor(s, 1, 64);
            s += __shfl_xor(s, 2, 64);
            s += __shfl_xor(s, 4, 64);
            s += __shfl_xor(s, 8, 64);
            sred[mf][i] = s;
        }
    }
    // aux_lds reused as red_lds: all aux reads (idx) completed pre-K-loop;
    // the lone in-loop aux-adjacent read (row 127, kt=9, lg=3) is masked.
    __syncthreads();
    #pragma unroll
    for (int mf = 0; mf < 4; ++mf)
        #pragma unroll
        for (int i = 0; i < 4; ++i)
            if (lr == 0) red_lds[wn][wm * 64 + mf * 16 + lg * 4 + i] = sred[mf][i];
    __syncthreads();
    for (int r = tid; r < BM; r += TPB) {
        float s = ba[0] + red_lds[0][r] + red_lds[1][r] + red_lds[2][r] + red_lds[3][r];
        scores[m0 + r] = s;
    }
}

// ---------------------------------------------------------------------------
// Kernel B: softmax over the TIME axis, in place on the attn region.
// ---------------------------------------------------------------------------
__global__ __launch_bounds__(64) void softmax_time_kernel(float* __restrict__ a)
{
    const int b = blockIdx.x / Pdim;
    const int p = blockIdx.x - b * Pdim;
    const int lane = threadIdx.x;
    const size_t base = (size_t)b * Tdim * Pdim + p;

    float v[4];
    float m = -1e30f;
    #pragma unroll
    for (int i = 0; i < 4; ++i) {
        int t = lane + i * 64;
        v[i] = (t < Tdim) ? a[base + (size_t)t * Pdim] : -1e30f;
        m = fmaxf(m, v[i]);
    }
    #pragma unroll
    for (int off = 32; off > 0; off >>= 1) m = fmaxf(m, __shfl_xor(m, off, 64));

    float s = 0.f;
    #pragma unroll
    for (int i = 0; i < 4; ++i) {
        int t = lane + i * 64;
        if (t < Tdim) { v[i] = expf(v[i] - m); s += v[i]; }
    }
    #pragma unroll
    for (int off = 32; off > 0; off >>= 1) s += __shfl_xor(s, off, 64);

    const float inv = 1.f / s;
    #pragma unroll
    for (int i = 0; i < 4; ++i) {
        int t = lane + i * 64;
        if (t < Tdim) a[base + (size_t)t * Pdim] = v[i] * inv;
    }
}

// ---------------------------------------------------------------------------
// Kernel C+D v5 (ES path): out[s] = sum_p attn[p] * ES[bt*100+p][s] + bsk[s].
// ES tile (100x32 fp32 = 12.8 KB) streamed to LDS (+1 pad -> stride 33);
// kc / gate / pred tails lane-parallel as in v4. ~26 KB LDS.
// ---------------------------------------------------------------------------
__global__ __launch_bounds__(512, 4) void cvpred5_kernel(
    const float* __restrict__ x,
    const float* __restrict__ ES,
    const float* __restrict__ attn,
    const float* __restrict__ bsk,
    const float* __restrict__ Wkc, const float* __restrict__ bkc,
    const float* __restrict__ Wpr, const float* __restrict__ bpr,
    float* __restrict__ res, float* __restrict__ res2, float* __restrict__ kcm)
{
    const int bt_i = blockIdx.x;           // 0..B*T-1
    const int tid  = threadIdx.x;

    __shared__ float es_lds[Pdim * 33];        // 13200 B (stride 33: no bank conflict)
    __shared__ float wkc_lds[Qdim * SKILL];    //  6000 B
    __shared__ float wpr_lds[SKILL * OUTD];    //  6000 B
    __shared__ float attn_lds[Pdim];
    __shared__ float x_lds[Qdim];
    __shared__ float zk_lds[SKILL], o_lds[SKILL], r2_lds[SKILL];

    // ---- stage (all independent, coalesced) ----
    {
        const float* src = ES + (size_t)bt_i * (Pdim * ESW);
        #pragma unroll
        for (int pos = tid; pos < Pdim * ESW; pos += 512)
            es_lds[(pos >> 5) * 33 + (pos & 31)] = src[pos];
    }
    for (int i = tid; i < (Qdim * SKILL) / 4; i += 512)
        ((float4*)wkc_lds)[i] = ((const float4*)Wkc)[i];
    for (int i = tid; i < (SKILL * OUTD) / 4; i += 512)
        ((float4*)wpr_lds)[i] = ((const float4*)Wpr)[i];
    if (tid < Pdim) attn_lds[tid] = attn[(size_t)bt_i * Pdim + tid];
    if (tid >= 128 && tid < 128 + Qdim) x_lds[tid - 128] = x[(size_t)bt_i * Qdim + tid - 128];
    __syncthreads();

    // ---- out[s] = attn . ES[:,s]  (30 s x 16 lanes, shfl reduce) ----
    if (tid < 480) {
        const int s = tid >> 4, l = tid & 15;
        float o = 0.f;
        #pragma unroll
        for (int k = 0; k < 7; ++k) {
            int p = l + 16 * k;
            if (p < Pdim) o = fmaf(attn_lds[p], es_lds[p * 33 + s], o);
        }
        o += __shfl_xor(o, 8, 64);
        o += __shfl_xor(o, 4, 64);
        o += __shfl_xor(o, 2, 64);
        o += __shfl_xor(o, 1, 64);
        if (l == 0) o_lds[s] = o + bsk[s];
    }
    // ---- zk[s] = x . Wkc[:,s]  (30 x 8) ----
    if (tid < 240) {
        const int s = tid >> 3, l = tid & 7;
        float zk = 0.f;
        #pragma unroll
        for (int j = 0; j < 7; ++j) {
            int q = l + 8 * j;
            if (q < Qdim) zk = fmaf(x_lds[q], wkc_lds[q * SKILL + s], zk);
        }
        zk += __shfl_xor(zk, 4, 64);
        zk += __shfl_xor(zk, 2, 64);
        zk += __shfl_xor(zk, 1, 64);
        if (l == 0) zk_lds[s] = zk + bkc[s];
    }
    __syncthreads();

    // ---- gate + writes ----
    if (tid < SKILL) {
        float zk = zk_lds[tid];
        float r2 = (zk >= 0.f) ? o_lds[tid] : 0.f;  // sigmoid(zk)>=0.5 <=> zk>=0
        kcm [(size_t)bt_i * SKILL + tid] = sigmoidf_(zk);
        res2[(size_t)bt_i * SKILL + tid] = r2;
        r2_lds[tid] = r2;
    }
    __syncthreads();

    // ---- res[o] = sigmoid(r2 . Wpr[:,o] + bpr)  (50 x 8) ----
    if (tid < 400) {
        const int od = tid >> 3, l = tid & 7;
        float z = 0.f;
        #pragma unroll
        for (int j = 0; j < 4; ++j) {
            int s = l + 8 * j;
            if (s < SKILL) z = fmaf(r2_lds[s], wpr_lds[s * OUTD + od], z);
        }
        z += __shfl_xor(z, 4, 64);
        z += __shfl_xor(z, 2, 64);
        z += __shfl_xor(z, 1, 64);
        if (l == 0) res[(size_t)bt_i * OUTD + od] = sigmoidf_(z + bpr[od]);
    }
}

// ---------------------------------------------------------------------------
// Fallback C+D (gather path, from round 7/8): used only if ws is too small.
// ---------------------------------------------------------------------------
__global__ __launch_bounds__(512, 4) void cvpred4_kernel(
    const float*  __restrict__ x,
    const int*    __restrict__ c2v,
    const float*  __restrict__ en,
    const float*  __restrict__ ep,
    const float*  __restrict__ attn,
    const float* __restrict__ Wsk, const float* __restrict__ bsk,
    const float* __restrict__ Wkc, const float* __restrict__ bkc,
    const float* __restrict__ Wpr, const float* __restrict__ bpr,
    float* __restrict__ res, float* __restrict__ res2, float* __restrict__ kcm)
{
    const int bt_i = blockIdx.x;
    const int tid  = threadIdx.x;

    __shared__ float  wsk_lds[Ddim * SKILL];
    __shared__ float  wkc_lds[Qdim * SKILL];
    __shared__ float  wpr_lds[SKILL * OUTD];
    __shared__ int    idx_lds[Pdim * 3];
    __shared__ float  attn_lds[Pdim];
    __shared__ float  x_lds[Qdim];
    __shared__ float4 part_lds[6][76];
    __shared__ float  cv_lds[Ddim];
    __shared__ float  zk_lds[SKILL], o_lds[SKILL], r2_lds[SKILL];

    const int pg = tid / 75;
    const int ch = tid - pg * 75;

    for (int i = tid; i < (Ddim * SKILL) / 4; i += 512)
        ((float4*)wsk_lds)[i] = ((const float4*)Wsk)[i];
    for (int i = tid; i < (Qdim * SKILL) / 4; i += 512)
        ((float4*)wkc_lds)[i] = ((const float4*)Wkc)[i];
    for (int i = tid; i < (SKILL * OUTD) / 4; i += 512)
        ((float4*)wpr_lds)[i] = ((const float4*)Wpr)[i];
    if (tid < Pdim * 3) idx_lds[tid] = c2v[(size_t)bt_i * (Pdim * 3) + tid];
    if (tid >= 320 && tid < 320 + Pdim) attn_lds[tid - 320] = attn[(size_t)bt_i * Pdim + tid - 320];
    if (tid >= 448 && tid < 448 + Qdim) x_lds[tid - 448] = x[(size_t)bt_i * Qdim + tid - 448];
    __syncthreads();

    if (pg < 6) {
        const int seg = ch / 25, cq = ch - seg * 25;
        const float* tab = (seg == 2) ? ep : en;
        const int io = (seg == 0) ? 0 : (seg == 1) ? 2 : 1;
        int   ri[17];
        float rw[17];
        #pragma unroll
        for (int k = 0; k < 17; ++k) {
            int p = pg + 6 * k;
            bool ok = (p < Pdim);
            ri[k] = idx_lds[(ok ? p : 0) * 3 + io];
            rw[k] = ok ? attn_lds[p] : 0.f;
        }
        float4 acc = {0.f, 0.f, 0.f, 0.f};
        {
            float4 va[9];
            #pragma unroll
            for (int k = 0; k < 9; ++k)
                va[k] = *(const float4*)&tab[(size_t)ri[k] * EMB + cq * 4];
            #pragma unroll
            for (int k = 0; k < 9; ++k) {
                acc.x = fmaf(rw[k], va[k].x, acc.x);
                acc.y = fmaf(rw[k], va[k].y, acc.y);
                acc.z = fmaf(rw[k], va[k].z, acc.z);
                acc.w = fmaf(rw[k], va[k].w, acc.w);
            }
        }
        {
            float4 vb[8];
            #pragma unroll
            for (int k = 0; k < 8; ++k)
                vb[k] = *(const float4*)&tab[(size_t)ri[k + 9] * EMB + cq * 4];
            #pragma unroll
            for (int k = 0; k < 8; ++k) {
                acc.x = fmaf(rw[k + 9], vb[k].x, acc.x);
                acc.y = fmaf(rw[k + 9], vb[k].y, acc.y);
                acc.z = fmaf(rw[k + 9], vb[k].z, acc.z);
                acc.w = fmaf(rw[k + 9], vb[k].w, acc.w);
            }
        }
        part_lds[pg][ch] = acc;
    }
    __syncthreads();

    if (tid < 75) {
        float4 a0 = part_lds[0][tid], a1 = part_lds[1][tid];
        float4 a2 = part_lds[2][tid], a3 = part_lds[3][tid];
        float4 a4 = part_lds[4][tid], a5 = part_lds[5][tid];
        int c = tid * 4;
        cv_lds[c + 0] = a0.x + a1.x + a2.x + a3.x + a4.x + a5.x;
        cv_lds[c + 1] = a0.y + a1.y + a2.y + a3.y + a4.y + a5.y;
        cv_lds[c + 2] = a0.z + a1.z + a2.z + a3.z + a4.z + a5.z;
        cv_lds[c + 3] = a0.w + a1.w + a2.w + a3.w + a4.w + a5.w;
    }
    __syncthreads();

    if (tid < 480) {
        const int s = tid >> 4, l = tid & 15;
        float o = 0.f;
        #pragma unroll
        for (int j = 0; j < 19; ++j) {
            int c = l + 16 * j;
            if (c < Ddim) o = fmaf(cv_lds[c], wsk_lds[c * SKILL + s], o);
        }
        o += __shfl_xor(o, 8, 64);
        o += __shfl_xor(o, 4, 64);
        o += __shfl_xor(o, 2, 64);
        o += __shfl_xor(o, 1, 64);
        if (l == 0) o_lds[s] = o + bsk[s];
    }
    if (tid < 240) {
        const int s = tid >> 3, l = tid & 7;
        float zk = 0.f;
        #pragma unroll
        for (int j = 0; j < 7; ++j) {
            int q = l + 8 * j;
            if (q < Qdim) zk = fmaf(x_lds[q], wkc_lds[q * SKILL + s], zk);
        }
        zk += __shfl_xor(zk, 4, 64);
        zk += __shfl_xor(zk, 2, 64);
        zk += __shfl_xor(zk, 1, 64);
        if (l == 0) zk_lds[s] = zk + bkc[s];
    }
    __syncthreads();

    if (tid < SKILL) {
        float zk = zk_lds[tid];
        float r2 = (zk >= 0.f) ? o_lds[tid] : 0.f;
        kcm [(size_t)bt_i * SKILL + tid] = sigmoidf_(zk);
        res2[(size_t)bt_i * SKILL + tid] = r2;
        r2_lds[tid] = r2;
    }
    __syncthreads();

    if (tid < 400) {
        const int od = tid >> 3, l = tid & 7;
        float z = 0.f;
        #pragma unroll
        for (int j = 0; j < 4; ++j) {
            int s = l + 8 * j;
            if (s < SKILL) z = fmaf(r2_lds[s], wpr_lds[s * OUTD + od], z);
        }
        z += __shfl_xor(z, 4, 64);
        z += __shfl_xor(z, 2, 64);
        z += __shfl_xor(z, 1, 64);
        if (l == 0) res[(size_t)bt_i * OUTD + od] = sigmoidf_(z + bpr[od]);
    }
}

// ---------------------------------------------------------------------------
extern "C" void kernel_launch(void* const* d_in, const int* in_sizes, int n_in,
                              void* d_out, int out_size, void* d_ws, size_t ws_size,
                              hipStream_t stream)
{
    const float* x   = (const float*)d_in[0];
    const int*   c2v = (const int*)  d_in[1];
    const float* en  = (const float*)d_in[2];
    const float* ep  = (const float*)d_in[3];
    const float* Wt  = (const float*)d_in[4];
    const float* bt  = (const float*)d_in[5];
    const float* Wa  = (const float*)d_in[6];
    const float* ba  = (const float*)d_in[7];
    const float* Wsk = (const float*)d_in[8];
    const float* bsk = (const float*)d_in[9];
    const float* Wkc = (const float*)d_in[10];
    const float* bkc = (const float*)d_in[11];
    const float* Wpr = (const float*)d_in[12];
    const float* bpr = (const float*)d_in[13];

    float* out  = (float*)d_out;
    float* res  = out + OFF_RES;
    float* res2 = out + OFF_RES2;
    float* kcm  = out + OFF_KC;
    float* attn = out + OFF_ATTN;

    __bf16* wbt   = (__bf16*)d_ws;                      // 225280 B
    float*  es_ws = (float*)((char*)d_ws + WBT_BYTES);  // 41 MB fp32 ES spill

    const bool use_es = ws_size >= WBT_BYTES + ES_BYTES;

    prep_wbt_kernel<<<(WROWS * KPAD + 255) / 256, 256, 0, stream>>>(Wt, Wsk, wbt);

    if (use_es)
        score_mfma_kernel<true><<<NROWS / BM, TPB, 0, stream>>>(
            c2v, en, ep, wbt, bt, Wa, ba, attn, es_ws);
    else
        score_mfma_kernel<false><<<NROWS / BM, TPB, 0, stream>>>(
            c2v, en, ep, wbt, bt, Wa, ba, attn, es_ws);

    softmax_time_kernel<<<Bdim * Pdim, 64, 0, stream>>>(attn);

    if (use_es)
        cvpred5_kernel<<<Bdim * Tdim, 512, 0, stream>>>(
            x, es_ws, attn, bsk, Wkc, bkc, Wpr, bpr, res, res2, kcm);
    else
        cvpred4_kernel<<<Bdim * Tdim, 512, 0, stream>>>(
            x, c2v, en, ep, attn, Wsk, bsk, Wkc, bkc, Wpr, bpr, res, res2, kcm);
}

// Round 12
// 324.797 us; speedup vs baseline: 1.2941x; 1.2941x over previous
//
#include <hip/hip_runtime.h>
#include <hip/hip_bf16.h>
#include <math.h>

#define Bdim 16
#define Tdim 200
#define Pdim 100
#define EMB  100
#define Ddim 300
#define SKILL 30
#define Qdim 50
#define OUTD 50

// d_out layout (floats), concatenated in reference return order:
// res [B,T,50], res2 [B,T,30], kc_mask [B,T,30], attn [B,T,P,1]
#define OFF_RES   0
#define OFF_RES2  (Bdim*Tdim*OUTD)              // 160000
#define OFF_KC    (OFF_RES2 + Bdim*Tdim*SKILL)  // 256000
#define OFF_ATTN  (OFF_KC + Bdim*Tdim*SKILL)    // 352000

typedef __bf16 bf16x8 __attribute__((ext_vector_type(8)));
typedef __bf16 bf16x4 __attribute__((ext_vector_type(4)));
typedef float  f32x4  __attribute__((ext_vector_type(4)));

// MFMA geometry for the score GEMM
#define BM    128          // rows per block
#define KPAD  320          // padded K of wbt rows
#define WROWS 352          // wbt rows: 0..319 = W_trans^T, 320..351 = Wsk^T
#define ASTR  312          // A row stride in bf16 (624 B)
#define TPB   512          // 8 waves
#define ESW   32           // ES row width (30 skills padded to 32 fp32)
#define ESSTR 36           // ES LDS staging stride (floats; 144 B, 16B-aligned)

#define NROWS (Bdim*Tdim*Pdim)                  // 320000
#define EN_ELEMS (20002*EMB)                    // 2,000,200
#define EP_ELEMS (50002*EMB)                    // 5,000,200

#define WBT_BYTES ((size_t)WROWS*KPAD*2)        // 225,280
#define ENB_BYTES ((size_t)EN_ELEMS*2)          // 4,000,400
#define EPB_BYTES ((size_t)EP_ELEMS*2)          // 10,000,400
#define ES_BYTES  ((size_t)NROWS*ESW*4)         // 40,960,000
#define WS_NEED   (WBT_BYTES+ENB_BYTES+EPB_BYTES+ES_BYTES)

__device__ __forceinline__ float fast_tanh(float x) {
    float t = __expf(2.0f * x);
    return 1.0f - 2.0f * __builtin_amdgcn_rcpf(t + 1.0f);
}
__device__ __forceinline__ float sigmoidf_(float z) {
    return 1.f / (1.f + expf(-z));
}

// ---------------------------------------------------------------------------
// Prep 1: wbt[j][k] bf16 (stride KPAD): rows 0..319 = W_trans^T (zeros pad),
// rows 320..351 = Wsk^T. k-pad zeros make A-side garbage harmless.
// ---------------------------------------------------------------------------
__global__ __launch_bounds__(256) void prep_wbt_kernel(
    const float* __restrict__ Wt, const float* __restrict__ Wsk,
    __bf16* __restrict__ wbt)
{
    int id = blockIdx.x * 256 + threadIdx.x;
    if (id >= WROWS * KPAD) return;
    int j = id / KPAD, k = id - j * KPAD;
    float v = 0.0f;
    if (j < KPAD) {
        if (j < Ddim && k < Ddim) v = Wt[k * Ddim + j];
    } else {
        int s = j - KPAD;
        if (s < SKILL && k < Ddim) v = Wsk[k * SKILL + s];
    }
    wbt[id] = (__bf16)v;
}

// ---------------------------------------------------------------------------
// Prep 2: embedding tables fp32 -> bf16 (halves gather fetch; en fits L2).
// ---------------------------------------------------------------------------
__global__ __launch_bounds__(256) void prep_tables_kernel(
    const float* __restrict__ en, const float* __restrict__ ep,
    __bf16* __restrict__ enb, __bf16* __restrict__ epb)
{
    int id = blockIdx.x * 256 + threadIdx.x;           // one 4-elem chunk
    const int entot = EN_ELEMS / 4;
    const int total = entot + EP_ELEMS / 4;
    if (id >= total) return;
    const float* s; __bf16* d; int off;
    if (id < entot) { s = en; d = enb; off = id * 4; }
    else            { s = ep; d = epb; off = (id - entot) * 4; }
    float4 v = *(const float4*)(s + off);
    bf16x4 b = { (__bf16)v.x, (__bf16)v.y, (__bf16)v.z, (__bf16)v.w };
    *(bf16x4*)(d + off) = b;
}

// ---------------------------------------------------------------------------
// Kernel A (MFMA): scores + optional ES = E @ Wsk spill.
// Main K-loop unchanged from r9 (proven 196 us). ES computed in a POST-loop
// (register lifetimes disjoint from main loop), staged via LDS, written
// coalesced. Gather reads bf16 tables when BT (pure copy, half the bytes).
// ---------------------------------------------------------------------------
template <bool WRITE_ES, bool BT>
__global__ __launch_bounds__(TPB, 4) void score_mfma_kernel(
    const int*    __restrict__ c2v,
    const float*  __restrict__ en,  const float*  __restrict__ ep,
    const __bf16* __restrict__ enb, const __bf16* __restrict__ epb,
    const __bf16* __restrict__ wbt,
    const float*  __restrict__ bt,
    const float*  __restrict__ wa,
    const float*  __restrict__ ba,
    float* __restrict__ scores,
    float* __restrict__ es_out)
{
    __shared__ __align__(16) __bf16 A_lds[BM * ASTR];   // 79872 B
    __shared__ __align__(16) char   aux_lds[2048];      // idx (early) / red (late)
    int*  idx_lds = (int*)aux_lds;                      // [BM*3] = 1536 B
    float (*red_lds)[BM] = (float (*)[BM])aux_lds;      // [4][BM] = 2048 B
    float* es_stage = (float*)A_lds;                    // [128][ESSTR] after A dead

    const int tid = threadIdx.x;
    const int m0  = blockIdx.x * BM;

    if (tid < BM * 3) idx_lds[tid] = c2v[(size_t)m0 * 3 + tid];
    __syncthreads();

    // ---- gather embeddings -> bf16 A tile (VALU-lean, reg-batched) ----
    {
        const int r   = tid >> 2;        // row
        const int sub = tid & 3;         // quarter
        const int i0 = idx_lds[r * 3 + 0];
        const int i1 = idx_lds[r * 3 + 1];
        const int i2 = idx_lds[r * 3 + 2];
        __bf16* arow = &A_lds[r * ASTR];
        if (BT) {
            const __bf16* srcs[3] = { enb + (size_t)i0 * EMB,
                                      enb + (size_t)i2 * EMB,
                                      epb + (size_t)i1 * EMB };
            #pragma unroll
            for (int seg = 0; seg < 3; ++seg) {
                const __bf16* src = srcs[seg];
                bf16x4 v[7];
                #pragma unroll
                for (int k = 0; k < 7; ++k) {
                    int j = sub + 4 * k;
                    if (j < 25) v[k] = *(const bf16x4*)(src + j * 4);
                }
                #pragma unroll
                for (int k = 0; k < 7; ++k) {
                    int j = sub + 4 * k;
                    if (j < 25) *(bf16x4*)(arow + seg * 100 + j * 4) = v[k];
                }
            }
        } else {
            const float* srcs[3] = { en + (size_t)i0 * EMB,
                                     en + (size_t)i2 * EMB,
                                     ep + (size_t)i1 * EMB };
            #pragma unroll
            for (int seg = 0; seg < 3; ++seg) {
                const float* src = srcs[seg];
                float4 v[7];
                #pragma unroll
                for (int k = 0; k < 7; ++k) {
                    int j = sub + 4 * k;
                    if (j < 25) v[k] = *(const float4*)(src + j * 4);
                }
                #pragma unroll
                for (int k = 0; k < 7; ++k) {
                    int j = sub + 4 * k;
                    if (j < 25) {
                        float4 w = v[k];
                        bf16x4 b4 = { (__bf16)w.x, (__bf16)w.y, (__bf16)w.z, (__bf16)w.w };
                        *(bf16x4*)(arow + seg * 100 + j * 4) = b4;
                    }
                }
            }
        }
        if (sub < 3) *(bf16x4*)(arow + 300 + sub * 4) = (bf16x4){};  // NaN hygiene
    }
    __syncthreads();

    const int wid = tid >> 6, lane = tid & 63;
    const int wm = wid >> 2, wn = wid & 3;       // 2 x 4 wave grid
    const int lr = lane & 15, lg = lane >> 4;
    const bool do_es = WRITE_ES && (wn < 2);

    f32x4 acc[4][5];
    #pragma unroll
    for (int mf = 0; mf < 4; ++mf)
        #pragma unroll
        for (int nf = 0; nf < 5; ++nf) acc[mf][nf] = (f32x4){0.f, 0.f, 0.f, 0.f};

    // ---- main barrier-free K-loop (identical to r9's proven loop) ----
    #pragma unroll
    for (int kt = 0; kt < 10; ++kt) {
        const int k0 = kt * 32;
        bf16x8 bfr[5];
        #pragma unroll
        for (int nf = 0; nf < 5; ++nf)
            bfr[nf] = *(const bf16x8*)&wbt[(size_t)(wn * 80 + nf * 16 + lr) * KPAD + k0 + lg * 8];
        bf16x8 af[4];
        #pragma unroll
        for (int mf = 0; mf < 4; ++mf) {
            bf16x8 a = *(const bf16x8*)&A_lds[(wm * 64 + mf * 16 + lr) * ASTR + k0 + lg * 8];
            if (kt == 9 && lg == 3) a = (bf16x8){};
            af[mf] = a;
        }
        #pragma unroll
        for (int mf = 0; mf < 4; ++mf)
            #pragma unroll
            for (int nf = 0; nf < 5; ++nf)
                acc[mf][nf] = __builtin_amdgcn_mfma_f32_16x16x32_bf16(
                    af[mf], bfr[nf], acc[mf][nf], 0, 0, 0);
    }

    // ---- ES post-loop (wn<2 only): register lifetime disjoint from above ----
    f32x4 acc_es[4];
    #pragma unroll
    for (int mf = 0; mf < 4; ++mf) acc_es[mf] = (f32x4){0.f, 0.f, 0.f, 0.f};
    if (do_es) {
        #pragma unroll
        for (int kt = 0; kt < 10; ++kt) {
            const int k0 = kt * 32;
            bf16x8 bes = *(const bf16x8*)&wbt[(size_t)(KPAD + wn * 16 + lr) * KPAD + k0 + lg * 8];
            #pragma unroll
            for (int mf = 0; mf < 4; ++mf) {
                bf16x8 a = *(const bf16x8*)&A_lds[(wm * 64 + mf * 16 + lr) * ASTR + k0 + lg * 8];
                if (kt == 9 && lg == 3) a = (bf16x8){};
                acc_es[mf] = __builtin_amdgcn_mfma_f32_16x16x32_bf16(
                    a, bes, acc_es[mf], 0, 0, 0);
            }
        }
    }

    // ---- epilogue: tanh * W_att, reduce over columns ----
    float btv[5], wav[5];
    #pragma unroll
    for (int nf = 0; nf < 5; ++nf) {
        int c = wn * 80 + nf * 16 + lr;
        bool ok = (c < Ddim);
        btv[nf] = ok ? bt[c] : 0.f;
        wav[nf] = ok ? wa[c] : 0.f;
    }
    float sred[4][4];
    #pragma unroll
    for (int mf = 0; mf < 4; ++mf) {
        #pragma unroll
        for (int i = 0; i < 4; ++i) {
            float s = 0.f;
            #pragma unroll
            for (int nf = 0; nf < 5; ++nf)
                s += fast_tanh(acc[mf][nf][i] + btv[nf]) * wav[nf];
            s += __shfl_xor(s, 1, 64);
            s += __shfl_xor(s, 2, 64);
            s += __shfl_xor(s, 4, 64);
            s += __shfl_xor(s, 8, 64);
            sred[mf][i] = s;
        }
    }
    // barrier 1: all waves done with A_lds / idx; recycle as red + es_stage
    __syncthreads();
    #pragma unroll
    for (int mf = 0; mf < 4; ++mf)
        #pragma unroll
        for (int i = 0; i < 4; ++i)
            if (lr == 0) red_lds[wn][wm * 64 + mf * 16 + lg * 4 + i] = sred[mf][i];
    if (do_es) {
        #pragma unroll
        for (int mf = 0; mf < 4; ++mf)
            #pragma unroll
            for (int i = 0; i < 4; ++i)
                es_stage[(wm * 64 + mf * 16 + lg * 4 + i) * ESSTR + wn * 16 + lr] = acc_es[mf][i];
    }
    __syncthreads();
    for (int r = tid; r < BM; r += TPB) {
        float s = ba[0] + red_lds[0][r] + red_lds[1][r] + red_lds[2][r] + red_lds[3][r];
        scores[m0 + r] = s;
    }
    if (WRITE_ES) {
        // coalesced float4 writeout of the staged ES tile
        #pragma unroll
        for (int pos = tid; pos < BM * 8; pos += TPB) {
            int row = pos >> 3, c4 = pos & 7;
            float4 v = *(const float4*)&es_stage[row * ESSTR + c4 * 4];
            *(float4*)&es_out[(size_t)(m0 + row) * ESW + c4 * 4] = v;
        }
    }
}

// ---------------------------------------------------------------------------
// Kernel B: softmax over TIME, one block per b; [T][P] slab staged in LDS
// (coalesced in/out), thread p does the serial max/exp/sum.
// ---------------------------------------------------------------------------
__global__ __launch_bounds__(512) void softmax_time_kernel(float* __restrict__ a)
{
    __shared__ float s_lds[Tdim * Pdim];     // 80000 B
    const int b = blockIdx.x, tid = threadIdx.x;
    float* base = a + (size_t)b * Tdim * Pdim;

    for (int i = tid; i < (Tdim * Pdim) / 4; i += 512)
        ((float4*)s_lds)[i] = ((const float4*)base)[i];
    __syncthreads();

    if (tid < Pdim) {
        const int p = tid;
        float m = -1e30f;
        for (int t = 0; t < Tdim; ++t) m = fmaxf(m, s_lds[t * Pdim + p]);
        float sum = 0.f;
        for (int t = 0; t < Tdim; ++t) {
            float e = expf(s_lds[t * Pdim + p] - m);
            s_lds[t * Pdim + p] = e;
            sum += e;
        }
        float inv = 1.f / sum;
        for (int t = 0; t < Tdim; ++t) s_lds[t * Pdim + p] *= inv;
    }
    __syncthreads();

    for (int i = tid; i < (Tdim * Pdim) / 4; i += 512)
        ((float4*)base)[i] = ((const float4*)s_lds)[i];
}

// ---------------------------------------------------------------------------
// Kernel C+D v5 (ES path): out[s] = sum_p attn[p]*ES[bt*100+p][s] + bsk[s].
// ---------------------------------------------------------------------------
__global__ __launch_bounds__(512, 4) void cvpred5_kernel(
    const float* __restrict__ x,
    const float* __restrict__ ES,
    const float* __restrict__ attn,
    const float* __restrict__ bsk,
    const float* __restrict__ Wkc, const float* __restrict__ bkc,
    const float* __restrict__ Wpr, const float* __restrict__ bpr,
    float* __restrict__ res, float* __restrict__ res2, float* __restrict__ kcm)
{
    const int bt_i = blockIdx.x;
    const int tid  = threadIdx.x;

    __shared__ float es_lds[Pdim * 33];        // stride 33: conflict-free
    __shared__ float wkc_lds[Qdim * SKILL];
    __shared__ float wpr_lds[SKILL * OUTD];
    __shared__ float attn_lds[Pdim];
    __shared__ float x_lds[Qdim];
    __shared__ float zk_lds[SKILL], o_lds[SKILL], r2_lds[SKILL];

    {
        const float* src = ES + (size_t)bt_i * (Pdim * ESW);
        #pragma unroll
        for (int pos = tid; pos < Pdim * ESW; pos += 512)
            es_lds[(pos >> 5) * 33 + (pos & 31)] = src[pos];
    }
    for (int i = tid; i < (Qdim * SKILL) / 4; i += 512)
        ((float4*)wkc_lds)[i] = ((const float4*)Wkc)[i];
    for (int i = tid; i < (SKILL * OUTD) / 4; i += 512)
        ((float4*)wpr_lds)[i] = ((const float4*)Wpr)[i];
    if (tid < Pdim) attn_lds[tid] = attn[(size_t)bt_i * Pdim + tid];
    if (tid >= 128 && tid < 128 + Qdim) x_lds[tid - 128] = x[(size_t)bt_i * Qdim + tid - 128];
    __syncthreads();

    if (tid < 480) {                       // o[s]: 30 s x 16 lanes
        const int s = tid >> 4, l = tid & 15;
        float o = 0.f;
        #pragma unroll
        for (int k = 0; k < 7; ++k) {
            int p = l + 16 * k;
            if (p < Pdim) o = fmaf(attn_lds[p], es_lds[p * 33 + s], o);
        }
        o += __shfl_xor(o, 8, 64);
        o += __shfl_xor(o, 4, 64);
        o += __shfl_xor(o, 2, 64);
        o += __shfl_xor(o, 1, 64);
        if (l == 0) o_lds[s] = o + bsk[s];
    }
    if (tid < 240) {                       // zk[s]: 30 x 8
        const int s = tid >> 3, l = tid & 7;
        float zk = 0.f;
        #pragma unroll
        for (int j = 0; j < 7; ++j) {
            int q = l + 8 * j;
            if (q < Qdim) zk = fmaf(x_lds[q], wkc_lds[q * SKILL + s], zk);
        }
        zk += __shfl_xor(zk, 4, 64);
        zk += __shfl_xor(zk, 2, 64);
        zk += __shfl_xor(zk, 1, 64);
        if (l == 0) zk_lds[s] = zk + bkc[s];
    }
    __syncthreads();

    if (tid < SKILL) {
        float zk = zk_lds[tid];
        float r2 = (zk >= 0.f) ? o_lds[tid] : 0.f;  // sigmoid(zk)>=0.5 <=> zk>=0
        kcm [(size_t)bt_i * SKILL + tid] = sigmoidf_(zk);
        res2[(size_t)bt_i * SKILL + tid] = r2;
        r2_lds[tid] = r2;
    }
    __syncthreads();

    if (tid < 400) {                       // res[o]: 50 x 8
        const int od = tid >> 3, l = tid & 7;
        float z = 0.f;
        #pragma unroll
        for (int j = 0; j < 4; ++j) {
            int s = l + 8 * j;
            if (s < SKILL) z = fmaf(r2_lds[s], wpr_lds[s * OUTD + od], z);
        }
        z += __shfl_xor(z, 4, 64);
        z += __shfl_xor(z, 2, 64);
        z += __shfl_xor(z, 1, 64);
        if (l == 0) res[(size_t)bt_i * OUTD + od] = sigmoidf_(z + bpr[od]);
    }
}

// ---------------------------------------------------------------------------
// Fallback C+D (fp32 gather, proven in r7/r8): used only if ws too small.
// ---------------------------------------------------------------------------
__global__ __launch_bounds__(512, 4) void cvpred4_kernel(
    const float*  __restrict__ x,
    const int*    __restrict__ c2v,
    const float*  __restrict__ en,
    const float*  __restrict__ ep,
    const float*  __restrict__ attn,
    const float* __restrict__ Wsk, const float* __restrict__ bsk,
    const float* __restrict__ Wkc, const float* __restrict__ bkc,
    const float* __restrict__ Wpr, const float* __restrict__ bpr,
    float* __restrict__ res, float* __restrict__ res2, float* __restrict__ kcm)
{
    const int bt_i = blockIdx.x;
    const int tid  = threadIdx.x;

    __shared__ float  wsk_lds[Ddim * SKILL];
    __shared__ float  wkc_lds[Qdim * SKILL];
    __shared__ float  wpr_lds[SKILL * OUTD];
    __shared__ int    idx_lds[Pdim * 3];
    __shared__ float  attn_lds[Pdim];
    __shared__ float  x_lds[Qdim];
    __shared__ float4 part_lds[6][76];
    __shared__ float  cv_lds[Ddim];
    __shared__ float  zk_lds[SKILL], o_lds[SKILL], r2_lds[SKILL];

    const int pg = tid / 75;
    const int ch = tid - pg * 75;

    for (int i = tid; i < (Ddim * SKILL) / 4; i += 512)
        ((float4*)wsk_lds)[i] = ((const float4*)Wsk)[i];
    for (int i = tid; i < (Qdim * SKILL) / 4; i += 512)
        ((float4*)wkc_lds)[i] = ((const float4*)Wkc)[i];
    for (int i = tid; i < (SKILL * OUTD) / 4; i += 512)
        ((float4*)wpr_lds)[i] = ((const float4*)Wpr)[i];
    if (tid < Pdim * 3) idx_lds[tid] = c2v[(size_t)bt_i * (Pdim * 3) + tid];
    if (tid >= 320 && tid < 320 + Pdim) attn_lds[tid - 320] = attn[(size_t)bt_i * Pdim + tid - 320];
    if (tid >= 448 && tid < 448 + Qdim) x_lds[tid - 448] = x[(size_t)bt_i * Qdim + tid - 448];
    __syncthreads();

    if (pg < 6) {
        const int seg = ch / 25, cq = ch - seg * 25;
        const float* tab = (seg == 2) ? ep : en;
        const int io = (seg == 0) ? 0 : (seg == 1) ? 2 : 1;
        int   ri[17];
        float rw[17];
        #pragma unroll
        for (int k = 0; k < 17; ++k) {
            int p = pg + 6 * k;
            bool ok = (p < Pdim);
            ri[k] = idx_lds[(ok ? p : 0) * 3 + io];
            rw[k] = ok ? attn_lds[p] : 0.f;
        }
        float4 acc = {0.f, 0.f, 0.f, 0.f};
        {
            float4 va[9];
            #pragma unroll
            for (int k = 0; k < 9; ++k)
                va[k] = *(const float4*)&tab[(size_t)ri[k] * EMB + cq * 4];
            #pragma unroll
            for (int k = 0; k < 9; ++k) {
                acc.x = fmaf(rw[k], va[k].x, acc.x);
                acc.y = fmaf(rw[k], va[k].y, acc.y);
                acc.z = fmaf(rw[k], va[k].z, acc.z);
                acc.w = fmaf(rw[k], va[k].w, acc.w);
            }
        }
        {
            float4 vb[8];
            #pragma unroll
            for (int k = 0; k < 8; ++k)
                vb[k] = *(const float4*)&tab[(size_t)ri[k + 9] * EMB + cq * 4];
            #pragma unroll
            for (int k = 0; k < 8; ++k) {
                acc.x = fmaf(rw[k + 9], vb[k].x, acc.x);
                acc.y = fmaf(rw[k + 9], vb[k].y, acc.y);
                acc.z = fmaf(rw[k + 9], vb[k].z, acc.z);
                acc.w = fmaf(rw[k + 9], vb[k].w, acc.w);
            }
        }
        part_lds[pg][ch] = acc;
    }
    __syncthreads();

    if (tid < 75) {
        float4 a0 = part_lds[0][tid], a1 = part_lds[1][tid];
        float4 a2 = part_lds[2][tid], a3 = part_lds[3][tid];
        float4 a4 = part_lds[4][tid], a5 = part_lds[5][tid];
        int c = tid * 4;
        cv_lds[c + 0] = a0.x + a1.x + a2.x + a3.x + a4.x + a5.x;
        cv_lds[c + 1] = a0.y + a1.y + a2.y + a3.y + a4.y + a5.y;
        cv_lds[c + 2] = a0.z + a1.z + a2.z + a3.z + a4.z + a5.z;
        cv_lds[c + 3] = a0.w + a1.w + a2.w + a3.w + a4.w + a5.w;
    }
    __syncthreads();

    if (tid < 480) {
        const int s = tid >> 4, l = tid & 15;
        float o = 0.f;
        #pragma unroll
        for (int j = 0; j < 19; ++j) {
            int c = l + 16 * j;
            if (c < Ddim) o = fmaf(cv_lds[c], wsk_lds[c * SKILL + s], o);
        }
        o += __shfl_xor(o, 8, 64);
        o += __shfl_xor(o, 4, 64);
        o += __shfl_xor(o, 2, 64);
        o += __shfl_xor(o, 1, 64);
        if (l == 0) o_lds[s] = o + bsk[s];
    }
    if (tid < 240) {
        const int s = tid >> 3, l = tid & 7;
        float zk = 0.f;
        #pragma unroll
        for (int j = 0; j < 7; ++j) {
            int q = l + 8 * j;
            if (q < Qdim) zk = fmaf(x_lds[q], wkc_lds[q * SKILL + s], zk);
        }
        zk += __shfl_xor(zk, 4, 64);
        zk += __shfl_xor(zk, 2, 64);
        zk += __shfl_xor(zk, 1, 64);
        if (l == 0) zk_lds[s] = zk + bkc[s];
    }
    __syncthreads();

    if (tid < SKILL) {
        float zk = zk_lds[tid];
        float r2 = (zk >= 0.f) ? o_lds[tid] : 0.f;
        kcm [(size_t)bt_i * SKILL + tid] = sigmoidf_(zk);
        res2[(size_t)bt_i * SKILL + tid] = r2;
        r2_lds[tid] = r2;
    }
    __syncthreads();

    if (tid < 400) {
        const int od = tid >> 3, l = tid & 7;
        float z = 0.f;
        #pragma unroll
        for (int j = 0; j < 4; ++j) {
            int s = l + 8 * j;
            if (s < SKILL) z = fmaf(r2_lds[s], wpr_lds[s * OUTD + od], z);
        }
        z += __shfl_xor(z, 4, 64);
        z += __shfl_xor(z, 2, 64);
        z += __shfl_xor(z, 1, 64);
        if (l == 0) res[(size_t)bt_i * OUTD + od] = sigmoidf_(z + bpr[od]);
    }
}

// ---------------------------------------------------------------------------
extern "C" void kernel_launch(void* const* d_in, const int* in_sizes, int n_in,
                              void* d_out, int out_size, void* d_ws, size_t ws_size,
                              hipStream_t stream)
{
    const float* x   = (const float*)d_in[0];
    const int*   c2v = (const int*)  d_in[1];
    const float* en  = (const float*)d_in[2];
    const float* ep  = (const float*)d_in[3];
    const float* Wt  = (const float*)d_in[4];
    const float* bt  = (const float*)d_in[5];
    const float* Wa  = (const float*)d_in[6];
    const float* ba  = (const float*)d_in[7];
    const float* Wsk = (const float*)d_in[8];
    const float* bsk = (const float*)d_in[9];
    const float* Wkc = (const float*)d_in[10];
    const float* bkc = (const float*)d_in[11];
    const float* Wpr = (const float*)d_in[12];
    const float* bpr = (const float*)d_in[13];

    float* out  = (float*)d_out;
    float* res  = out + OFF_RES;
    float* res2 = out + OFF_RES2;
    float* kcm  = out + OFF_KC;
    float* attn = out + OFF_ATTN;

    char* ws = (char*)d_ws;
    __bf16* wbt   = (__bf16*)ws;                                    // 225,280 B
    __bf16* enb   = (__bf16*)(ws + WBT_BYTES);                      // 4.0 MB
    __bf16* epb   = (__bf16*)(ws + WBT_BYTES + ENB_BYTES);          // 10.0 MB
    float*  es_ws = (float*)(ws + WBT_BYTES + ENB_BYTES + EPB_BYTES); // 41 MB

    const bool use_es = ws_size >= WS_NEED;

    prep_wbt_kernel<<<(WROWS * KPAD + 255) / 256, 256, 0, stream>>>(Wt, Wsk, wbt);

    if (use_es) {
        prep_tables_kernel<<<((EN_ELEMS + EP_ELEMS) / 4 + 255) / 256, 256, 0, stream>>>(
            en, ep, enb, epb);
        score_mfma_kernel<true, true><<<NROWS / BM, TPB, 0, stream>>>(
            c2v, en, ep, enb, epb, wbt, bt, Wa, ba, attn, es_ws);
    } else {
        score_mfma_kernel<false, false><<<NROWS / BM, TPB, 0, stream>>>(
            c2v, en, ep, enb, epb, wbt, bt, Wa, ba, attn, es_ws);
    }

    softmax_time_kernel<<<Bdim, 512, 0, stream>>>(attn);

    if (use_es)
        cvpred5_kernel<<<Bdim * Tdim, 512, 0, stream>>>(
            x, es_ws, attn, bsk, Wkc, bkc, Wpr, bpr, res, res2, kcm);
    else
        cvpred4_kernel<<<Bdim * Tdim, 512, 0, stream>>>(
            x, c2v, en, ep, attn, Wsk, bsk, Wkc, bkc, Wpr, bpr, res, res2, kcm);
}

// Round 13
// 307.454 us; speedup vs baseline: 1.3671x; 1.0564x over previous
//
#include <hip/hip_runtime.h>
#include <hip/hip_bf16.h>
#include <math.h>

#define Bdim 16
#define Tdim 200
#define Pdim 100
#define EMB  100
#define Ddim 300
#define SKILL 30
#define Qdim 50
#define OUTD 50

// d_out layout (floats), concatenated in reference return order:
// res [B,T,50], res2 [B,T,30], kc_mask [B,T,30], attn [B,T,P,1]
#define OFF_RES   0
#define OFF_RES2  (Bdim*Tdim*OUTD)              // 160000
#define OFF_KC    (OFF_RES2 + Bdim*Tdim*SKILL)  // 256000
#define OFF_ATTN  (OFF_KC + Bdim*Tdim*SKILL)    // 352000

typedef __bf16 bf16x8 __attribute__((ext_vector_type(8)));
typedef __bf16 bf16x4 __attribute__((ext_vector_type(4)));
typedef float  f32x4  __attribute__((ext_vector_type(4)));

// MFMA geometry for the score GEMM
#define BM    128          // rows per block
#define KPAD  320          // padded K of wbt rows
#define WROWS 352          // wbt rows: 0..319 = W_trans^T, 320..351 = Wsk^T
#define ASTR  312          // A row stride in bf16 (624 B)
#define TPB   512          // 8 waves
#define ESW   32           // ES row width (30 skills padded to 32 fp32)
#define ESSTR 36           // ES LDS staging stride (floats; 144 B, 16B-aligned)

#define NROWS (Bdim*Tdim*Pdim)                  // 320000
#define EN_ELEMS (20002*EMB)                    // 2,000,200
#define EP_ELEMS (50002*EMB)                    // 5,000,200

#define WBT_BYTES ((size_t)WROWS*KPAD*2)        // 225,280
#define ENB_BYTES ((size_t)EN_ELEMS*2)          // 4,000,400
#define EPB_BYTES ((size_t)EP_ELEMS*2)          // 10,000,400
#define ES_BYTES  ((size_t)NROWS*ESW*4)         // 40,960,000
#define WS_NEED   (WBT_BYTES+ENB_BYTES+EPB_BYTES+ES_BYTES)

#define WBT_IDS   (WROWS*KPAD)                  // 112,640
#define TAB_CHUNKS ((EN_ELEMS+EP_ELEMS)/4)      // 1,750,100

#define BTPB  4            // bt rows per cvpred6 block

__device__ __forceinline__ float fast_tanh(float x) {
    float t = __expf(2.0f * x);
    return 1.0f - 2.0f * __builtin_amdgcn_rcpf(t + 1.0f);
}
__device__ __forceinline__ float sigmoidf_(float z) {
    return 1.f / (1.f + expf(-z));
}

// ---------------------------------------------------------------------------
// Merged prep: ids [0, WBT_IDS) build wbt (W_trans^T rows 0..319, Wsk^T rows
// 320..351, zero-padded); ids beyond convert en/ep fp32 -> bf16 (4-elem
// chunks). n_tab = 0 when the ES path is disabled.
// ---------------------------------------------------------------------------
__global__ __launch_bounds__(256) void prep_all_kernel(
    const float* __restrict__ Wt, const float* __restrict__ Wsk,
    const float* __restrict__ en, const float* __restrict__ ep,
    __bf16* __restrict__ wbt, __bf16* __restrict__ enb, __bf16* __restrict__ epb,
    int n_tab)
{
    int id = blockIdx.x * 256 + threadIdx.x;
    if (id < WBT_IDS) {
        int j = id / KPAD, k = id - j * KPAD;
        float v = 0.0f;
        if (j < KPAD) {
            if (j < Ddim && k < Ddim) v = Wt[k * Ddim + j];
        } else {
            int s = j - KPAD;
            if (s < SKILL && k < Ddim) v = Wsk[k * SKILL + s];
        }
        wbt[id] = (__bf16)v;
        return;
    }
    int c = id - WBT_IDS;
    if (c >= n_tab) return;
    const int entot = EN_ELEMS / 4;
    const float* s; __bf16* d; int off;
    if (c < entot) { s = en; d = enb; off = c * 4; }
    else           { s = ep; d = epb; off = (c - entot) * 4; }
    float4 v = *(const float4*)(s + off);
    bf16x4 b = { (__bf16)v.x, (__bf16)v.y, (__bf16)v.z, (__bf16)v.w };
    *(bf16x4*)(d + off) = b;
}

// ---------------------------------------------------------------------------
// Kernel A (MFMA): scores + optional ES = E @ Wsk spill.  (UNCHANGED from
// r12 -- proven 194 us: barrier-free main K-loop, ES post-loop with disjoint
// register lifetimes, LDS-staged coalesced ES writeout, bf16-table gather.)
// ---------------------------------------------------------------------------
template <bool WRITE_ES, bool BT>
__global__ __launch_bounds__(TPB, 4) void score_mfma_kernel(
    const int*    __restrict__ c2v,
    const float*  __restrict__ en,  const float*  __restrict__ ep,
    const __bf16* __restrict__ enb, const __bf16* __restrict__ epb,
    const __bf16* __restrict__ wbt,
    const float*  __restrict__ bt,
    const float*  __restrict__ wa,
    const float*  __restrict__ ba,
    float* __restrict__ scores,
    float* __restrict__ es_out)
{
    __shared__ __align__(16) __bf16 A_lds[BM * ASTR];   // 79872 B
    __shared__ __align__(16) char   aux_lds[2048];      // idx (early) / red (late)
    int*  idx_lds = (int*)aux_lds;                      // [BM*3] = 1536 B
    float (*red_lds)[BM] = (float (*)[BM])aux_lds;      // [4][BM] = 2048 B
    float* es_stage = (float*)A_lds;                    // [128][ESSTR] after A dead

    const int tid = threadIdx.x;
    const int m0  = blockIdx.x * BM;

    if (tid < BM * 3) idx_lds[tid] = c2v[(size_t)m0 * 3 + tid];
    __syncthreads();

    // ---- gather embeddings -> bf16 A tile (VALU-lean, reg-batched) ----
    {
        const int r   = tid >> 2;        // row
        const int sub = tid & 3;         // quarter
        const int i0 = idx_lds[r * 3 + 0];
        const int i1 = idx_lds[r * 3 + 1];
        const int i2 = idx_lds[r * 3 + 2];
        __bf16* arow = &A_lds[r * ASTR];
        if (BT) {
            const __bf16* srcs[3] = { enb + (size_t)i0 * EMB,
                                      enb + (size_t)i2 * EMB,
                                      epb + (size_t)i1 * EMB };
            #pragma unroll
            for (int seg = 0; seg < 3; ++seg) {
                const __bf16* src = srcs[seg];
                bf16x4 v[7];
                #pragma unroll
                for (int k = 0; k < 7; ++k) {
                    int j = sub + 4 * k;
                    if (j < 25) v[k] = *(const bf16x4*)(src + j * 4);
                }
                #pragma unroll
                for (int k = 0; k < 7; ++k) {
                    int j = sub + 4 * k;
                    if (j < 25) *(bf16x4*)(arow + seg * 100 + j * 4) = v[k];
                }
            }
        } else {
            const float* srcs[3] = { en + (size_t)i0 * EMB,
                                     en + (size_t)i2 * EMB,
                                     ep + (size_t)i1 * EMB };
            #pragma unroll
            for (int seg = 0; seg < 3; ++seg) {
                const float* src = srcs[seg];
                float4 v[7];
                #pragma unroll
                for (int k = 0; k < 7; ++k) {
                    int j = sub + 4 * k;
                    if (j < 25) v[k] = *(const float4*)(src + j * 4);
                }
                #pragma unroll
                for (int k = 0; k < 7; ++k) {
                    int j = sub + 4 * k;
                    if (j < 25) {
                        float4 w = v[k];
                        bf16x4 b4 = { (__bf16)w.x, (__bf16)w.y, (__bf16)w.z, (__bf16)w.w };
                        *(bf16x4*)(arow + seg * 100 + j * 4) = b4;
                    }
                }
            }
        }
        if (sub < 3) *(bf16x4*)(arow + 300 + sub * 4) = (bf16x4){};  // NaN hygiene
    }
    __syncthreads();

    const int wid = tid >> 6, lane = tid & 63;
    const int wm = wid >> 2, wn = wid & 3;       // 2 x 4 wave grid
    const int lr = lane & 15, lg = lane >> 4;
    const bool do_es = WRITE_ES && (wn < 2);

    f32x4 acc[4][5];
    #pragma unroll
    for (int mf = 0; mf < 4; ++mf)
        #pragma unroll
        for (int nf = 0; nf < 5; ++nf) acc[mf][nf] = (f32x4){0.f, 0.f, 0.f, 0.f};

    // ---- main barrier-free K-loop ----
    #pragma unroll
    for (int kt = 0; kt < 10; ++kt) {
        const int k0 = kt * 32;
        bf16x8 bfr[5];
        #pragma unroll
        for (int nf = 0; nf < 5; ++nf)
            bfr[nf] = *(const bf16x8*)&wbt[(size_t)(wn * 80 + nf * 16 + lr) * KPAD + k0 + lg * 8];
        bf16x8 af[4];
        #pragma unroll
        for (int mf = 0; mf < 4; ++mf) {
            bf16x8 a = *(const bf16x8*)&A_lds[(wm * 64 + mf * 16 + lr) * ASTR + k0 + lg * 8];
            if (kt == 9 && lg == 3) a = (bf16x8){};
            af[mf] = a;
        }
        #pragma unroll
        for (int mf = 0; mf < 4; ++mf)
            #pragma unroll
            for (int nf = 0; nf < 5; ++nf)
                acc[mf][nf] = __builtin_amdgcn_mfma_f32_16x16x32_bf16(
                    af[mf], bfr[nf], acc[mf][nf], 0, 0, 0);
    }

    // ---- ES post-loop (wn<2 only): register lifetime disjoint ----
    f32x4 acc_es[4];
    #pragma unroll
    for (int mf = 0; mf < 4; ++mf) acc_es[mf] = (f32x4){0.f, 0.f, 0.f, 0.f};
    if (do_es) {
        #pragma unroll
        for (int kt = 0; kt < 10; ++kt) {
            const int k0 = kt * 32;
            bf16x8 bes = *(const bf16x8*)&wbt[(size_t)(KPAD + wn * 16 + lr) * KPAD + k0 + lg * 8];
            #pragma unroll
            for (int mf = 0; mf < 4; ++mf) {
                bf16x8 a = *(const bf16x8*)&A_lds[(wm * 64 + mf * 16 + lr) * ASTR + k0 + lg * 8];
                if (kt == 9 && lg == 3) a = (bf16x8){};
                acc_es[mf] = __builtin_amdgcn_mfma_f32_16x16x32_bf16(
                    a, bes, acc_es[mf], 0, 0, 0);
            }
        }
    }

    // ---- epilogue: tanh * W_att, reduce over columns ----
    float btv[5], wav[5];
    #pragma unroll
    for (int nf = 0; nf < 5; ++nf) {
        int c = wn * 80 + nf * 16 + lr;
        bool ok = (c < Ddim);
        btv[nf] = ok ? bt[c] : 0.f;
        wav[nf] = ok ? wa[c] : 0.f;
    }
    float sred[4][4];
    #pragma unroll
    for (int mf = 0; mf < 4; ++mf) {
        #pragma unroll
        for (int i = 0; i < 4; ++i) {
            float s = 0.f;
            #pragma unroll
            for (int nf = 0; nf < 5; ++nf)
                s += fast_tanh(acc[mf][nf][i] + btv[nf]) * wav[nf];
            s += __shfl_xor(s, 1, 64);
            s += __shfl_xor(s, 2, 64);
            s += __shfl_xor(s, 4, 64);
            s += __shfl_xor(s, 8, 64);
            sred[mf][i] = s;
        }
    }
    __syncthreads();
    #pragma unroll
    for (int mf = 0; mf < 4; ++mf)
        #pragma unroll
        for (int i = 0; i < 4; ++i)
            if (lr == 0) red_lds[wn][wm * 64 + mf * 16 + lg * 4 + i] = sred[mf][i];
    if (do_es) {
        #pragma unroll
        for (int mf = 0; mf < 4; ++mf)
            #pragma unroll
            for (int i = 0; i < 4; ++i)
                es_stage[(wm * 64 + mf * 16 + lg * 4 + i) * ESSTR + wn * 16 + lr] = acc_es[mf][i];
    }
    __syncthreads();
    for (int r = tid; r < BM; r += TPB) {
        float s = ba[0] + red_lds[0][r] + red_lds[1][r] + red_lds[2][r] + red_lds[3][r];
        scores[m0 + r] = s;
    }
    if (WRITE_ES) {
        #pragma unroll
        for (int pos = tid; pos < BM * 8; pos += TPB) {
            int row = pos >> 3, c4 = pos & 7;
            float4 v = *(const float4*)&es_stage[row * ESSTR + c4 * 4];
            *(float4*)&es_out[(size_t)(m0 + row) * ESW + c4 * 4] = v;
        }
    }
}

// ---------------------------------------------------------------------------
// Kernel B: softmax over the TIME axis -- REVERTED to the proven r9 design:
// one 64-lane wave per (b,p), 1600 blocks (chip-wide parallelism).
// ---------------------------------------------------------------------------
__global__ __launch_bounds__(64) void softmax_time_kernel(float* __restrict__ a)
{
    const int b = blockIdx.x / Pdim;
    const int p = blockIdx.x - b * Pdim;
    const int lane = threadIdx.x;
    const size_t base = (size_t)b * Tdim * Pdim + p;

    float v[4];
    float m = -1e30f;
    #pragma unroll
    for (int i = 0; i < 4; ++i) {
        int t = lane + i * 64;
        v[i] = (t < Tdim) ? a[base + (size_t)t * Pdim] : -1e30f;
        m = fmaxf(m, v[i]);
    }
    #pragma unroll
    for (int off = 32; off > 0; off >>= 1) m = fmaxf(m, __shfl_xor(m, off, 64));

    float s = 0.f;
    #pragma unroll
    for (int i = 0; i < 4; ++i) {
        int t = lane + i * 64;
        if (t < Tdim) { v[i] = expf(v[i] - m); s += v[i]; }
    }
    #pragma unroll
    for (int off = 32; off > 0; off >>= 1) s += __shfl_xor(s, off, 64);

    const float inv = 1.f / s;
    #pragma unroll
    for (int i = 0; i < 4; ++i) {
        int t = lane + i * 64;
        if (t < Tdim) a[base + (size_t)t * Pdim] = v[i] * inv;
    }
}

// ---------------------------------------------------------------------------
// Kernel C+D v6 (ES path): 4 consecutive bt per block (800 blocks).
// ES/attn/x for 4 bt are CONTIGUOUS -> one coalesced stage, weights staged
// once per 4 bt, single barrier set. out[s] = sum_p attn[p]*ES[p][s]+bsk[s].
// ---------------------------------------------------------------------------
__global__ __launch_bounds__(512, 2) void cvpred6_kernel(
    const float* __restrict__ x,
    const float* __restrict__ ES,
    const float* __restrict__ attn,
    const float* __restrict__ bsk,
    const float* __restrict__ Wkc, const float* __restrict__ bkc,
    const float* __restrict__ Wpr, const float* __restrict__ bpr,
    float* __restrict__ res, float* __restrict__ res2, float* __restrict__ kcm)
{
    const int bt0 = blockIdx.x * BTPB;     // first bt of this block
    const int tid = threadIdx.x;

    __shared__ float es_lds[BTPB * Pdim * 33];   // 52800 B (stride 33: conflict-free)
    __shared__ float wkc_lds[Qdim * SKILL];      //  6000 B
    __shared__ float wpr_lds[SKILL * OUTD];      //  6000 B
    __shared__ float attn_lds[BTPB * Pdim];      //  1600 B
    __shared__ float x_lds[BTPB * Qdim];         //   800 B
    __shared__ float zk_lds[BTPB * SKILL], o_lds[BTPB * SKILL], r2_lds[BTPB * SKILL];

    // ---- stage everything (all contiguous, coalesced) ----
    {
        const float* src = ES + (size_t)bt0 * (Pdim * ESW);
        #pragma unroll
        for (int pos = tid; pos < BTPB * Pdim * ESW; pos += 512) {
            int row = pos >> 5, col = pos & 31;      // row in [0,400)
            es_lds[row * 33 + col] = src[pos];
        }
    }
    for (int i = tid; i < (Qdim * SKILL) / 4; i += 512)
        ((float4*)wkc_lds)[i] = ((const float4*)Wkc)[i];
    for (int i = tid; i < (SKILL * OUTD) / 4; i += 512)
        ((float4*)wpr_lds)[i] = ((const float4*)Wpr)[i];
    if (tid < BTPB * Pdim) attn_lds[tid] = attn[(size_t)bt0 * Pdim + tid];
    if (tid >= 256 && tid < 256 + BTPB * Qdim)
        x_lds[tid - 256] = x[(size_t)bt0 * Qdim + (tid - 256)];
    __syncthreads();

    // ---- o[s] and zk[s] for all 4 bt ----
    #pragma unroll
    for (int b = 0; b < BTPB; ++b) {
        if (tid < 480) {                   // o[s]: 30 s x 16 lanes
            const int s = tid >> 4, l = tid & 15;
            float o = 0.f;
            #pragma unroll
            for (int k = 0; k < 7; ++k) {
                int p = l + 16 * k;
                if (p < Pdim)
                    o = fmaf(attn_lds[b * Pdim + p], es_lds[(b * Pdim + p) * 33 + s], o);
            }
            o += __shfl_xor(o, 8, 64);
            o += __shfl_xor(o, 4, 64);
            o += __shfl_xor(o, 2, 64);
            o += __shfl_xor(o, 1, 64);
            if (l == 0) o_lds[b * SKILL + s] = o + bsk[s];
        }
        if (tid < 240) {                   // zk[s]: 30 x 8
            const int s = tid >> 3, l = tid & 7;
            float zk = 0.f;
            #pragma unroll
            for (int j = 0; j < 7; ++j) {
                int q = l + 8 * j;
                if (q < Qdim) zk = fmaf(x_lds[b * Qdim + q], wkc_lds[q * SKILL + s], zk);
            }
            zk += __shfl_xor(zk, 4, 64);
            zk += __shfl_xor(zk, 2, 64);
            zk += __shfl_xor(zk, 1, 64);
            if (l == 0) zk_lds[b * SKILL + s] = zk + bkc[s];
        }
    }
    __syncthreads();

    // ---- gate + kcm/res2 writes (120 lanes = 4 bt x 30 s) ----
    if (tid < BTPB * SKILL) {
        const int b = tid / SKILL, s = tid - b * SKILL;
        float zk = zk_lds[tid];
        float r2 = (zk >= 0.f) ? o_lds[tid] : 0.f;  // sigmoid(zk)>=0.5 <=> zk>=0
        kcm [(size_t)(bt0 + b) * SKILL + s] = sigmoidf_(zk);
        res2[(size_t)(bt0 + b) * SKILL + s] = r2;
        r2_lds[tid] = r2;
    }
    __syncthreads();

    // ---- res[o] for all 4 bt (50 x 8) ----
    #pragma unroll
    for (int b = 0; b < BTPB; ++b) {
        if (tid < 400) {
            const int od = tid >> 3, l = tid & 7;
            float z = 0.f;
            #pragma unroll
            for (int j = 0; j < 4; ++j) {
                int s = l + 8 * j;
                if (s < SKILL) z = fmaf(r2_lds[b * SKILL + s], wpr_lds[s * OUTD + od], z);
            }
            z += __shfl_xor(z, 4, 64);
            z += __shfl_xor(z, 2, 64);
            z += __shfl_xor(z, 1, 64);
            if (l == 0) res[(size_t)(bt0 + b) * OUTD + od] = sigmoidf_(z + bpr[od]);
        }
    }
}

// ---------------------------------------------------------------------------
// Fallback C+D (fp32 gather, proven in r7/r8): used only if ws too small.
// ---------------------------------------------------------------------------
__global__ __launch_bounds__(512, 4) void cvpred4_kernel(
    const float*  __restrict__ x,
    const int*    __restrict__ c2v,
    const float*  __restrict__ en,
    const float*  __restrict__ ep,
    const float*  __restrict__ attn,
    const float* __restrict__ Wsk, const float* __restrict__ bsk,
    const float* __restrict__ Wkc, const float* __restrict__ bkc,
    const float* __restrict__ Wpr, const float* __restrict__ bpr,
    float* __restrict__ res, float* __restrict__ res2, float* __restrict__ kcm)
{
    const int bt_i = blockIdx.x;
    const int tid  = threadIdx.x;

    __shared__ float  wsk_lds[Ddim * SKILL];
    __shared__ float  wkc_lds[Qdim * SKILL];
    __shared__ float  wpr_lds[SKILL * OUTD];
    __shared__ int    idx_lds[Pdim * 3];
    __shared__ float  attn_lds[Pdim];
    __shared__ float  x_lds[Qdim];
    __shared__ float4 part_lds[6][76];
    __shared__ float  cv_lds[Ddim];
    __shared__ float  zk_lds[SKILL], o_lds[SKILL], r2_lds[SKILL];

    const int pg = tid / 75;
    const int ch = tid - pg * 75;

    for (int i = tid; i < (Ddim * SKILL) / 4; i += 512)
        ((float4*)wsk_lds)[i] = ((const float4*)Wsk)[i];
    for (int i = tid; i < (Qdim * SKILL) / 4; i += 512)
        ((float4*)wkc_lds)[i] = ((const float4*)Wkc)[i];
    for (int i = tid; i < (SKILL * OUTD) / 4; i += 512)
        ((float4*)wpr_lds)[i] = ((const float4*)Wpr)[i];
    if (tid < Pdim * 3) idx_lds[tid] = c2v[(size_t)bt_i * (Pdim * 3) + tid];
    if (tid >= 320 && tid < 320 + Pdim) attn_lds[tid - 320] = attn[(size_t)bt_i * Pdim + tid - 320];
    if (tid >= 448 && tid < 448 + Qdim) x_lds[tid - 448] = x[(size_t)bt_i * Qdim + tid - 448];
    __syncthreads();

    if (pg < 6) {
        const int seg = ch / 25, cq = ch - seg * 25;
        const float* tab = (seg == 2) ? ep : en;
        const int io = (seg == 0) ? 0 : (seg == 1) ? 2 : 1;
        int   ri[17];
        float rw[17];
        #pragma unroll
        for (int k = 0; k < 17; ++k) {
            int p = pg + 6 * k;
            bool ok = (p < Pdim);
            ri[k] = idx_lds[(ok ? p : 0) * 3 + io];
            rw[k] = ok ? attn_lds[p] : 0.f;
        }
        float4 acc = {0.f, 0.f, 0.f, 0.f};
        {
            float4 va[9];
            #pragma unroll
            for (int k = 0; k < 9; ++k)
                va[k] = *(const float4*)&tab[(size_t)ri[k] * EMB + cq * 4];
            #pragma unroll
            for (int k = 0; k < 9; ++k) {
                acc.x = fmaf(rw[k], va[k].x, acc.x);
                acc.y = fmaf(rw[k], va[k].y, acc.y);
                acc.z = fmaf(rw[k], va[k].z, acc.z);
                acc.w = fmaf(rw[k], va[k].w, acc.w);
            }
        }
        {
            float4 vb[8];
            #pragma unroll
            for (int k = 0; k < 8; ++k)
                vb[k] = *(const float4*)&tab[(size_t)ri[k + 9] * EMB + cq * 4];
            #pragma unroll
            for (int k = 0; k < 8; ++k) {
                acc.x = fmaf(rw[k + 9], vb[k].x, acc.x);
                acc.y = fmaf(rw[k + 9], vb[k].y, acc.y);
                acc.z = fmaf(rw[k + 9], vb[k].z, acc.z);
                acc.w = fmaf(rw[k + 9], vb[k].w, acc.w);
            }
        }
        part_lds[pg][ch] = acc;
    }
    __syncthreads();

    if (tid < 75) {
        float4 a0 = part_lds[0][tid], a1 = part_lds[1][tid];
        float4 a2 = part_lds[2][tid], a3 = part_lds[3][tid];
        float4 a4 = part_lds[4][tid], a5 = part_lds[5][tid];
        int c = tid * 4;
        cv_lds[c + 0] = a0.x + a1.x + a2.x + a3.x + a4.x + a5.x;
        cv_lds[c + 1] = a0.y + a1.y + a2.y + a3.y + a4.y + a5.y;
        cv_lds[c + 2] = a0.z + a1.z + a2.z + a3.z + a4.z + a5.z;
        cv_lds[c + 3] = a0.w + a1.w + a2.w + a3.w + a4.w + a5.w;
    }
    __syncthreads();

    if (tid < 480) {
        const int s = tid >> 4, l = tid & 15;
        float o = 0.f;
        #pragma unroll
        for (int j = 0; j < 19; ++j) {
            int c = l + 16 * j;
            if (c < Ddim) o = fmaf(cv_lds[c], wsk_lds[c * SKILL + s], o);
        }
        o += __shfl_xor(o, 8, 64);
        o += __shfl_xor(o, 4, 64);
        o += __shfl_xor(o, 2, 64);
        o += __shfl_xor(o, 1, 64);
        if (l == 0) o_lds[s] = o + bsk[s];
    }
    if (tid < 240) {
        const int s = tid >> 3, l = tid & 7;
        float zk = 0.f;
        #pragma unroll
        for (int j = 0; j < 7; ++j) {
            int q = l + 8 * j;
            if (q < Qdim) zk = fmaf(x_lds[q], wkc_lds[q * SKILL + s], zk);
        }
        zk += __shfl_xor(zk, 4, 64);
        zk += __shfl_xor(zk, 2, 64);
        zk += __shfl_xor(zk, 1, 64);
        if (l == 0) zk_lds[s] = zk + bkc[s];
    }
    __syncthreads();

    if (tid < SKILL) {
        float zk = zk_lds[tid];
        float r2 = (zk >= 0.f) ? o_lds[tid] : 0.f;
        kcm [(size_t)bt_i * SKILL + tid] = sigmoidf_(zk);
        res2[(size_t)bt_i * SKILL + tid] = r2;
        r2_lds[tid] = r2;
    }
    __syncthreads();

    if (tid < 400) {
        const int od = tid >> 3, l = tid & 7;
        float z = 0.f;
        #pragma unroll
        for (int j = 0; j < 4; ++j) {
            int s = l + 8 * j;
            if (s < SKILL) z = fmaf(r2_lds[s], wpr_lds[s * OUTD + od], z);
        }
        z += __shfl_xor(z, 4, 64);
        z += __shfl_xor(z, 2, 64);
        z += __shfl_xor(z, 1, 64);
        if (l == 0) res[(size_t)bt_i * OUTD + od] = sigmoidf_(z + bpr[od]);
    }
}

// ---------------------------------------------------------------------------
extern "C" void kernel_launch(void* const* d_in, const int* in_sizes, int n_in,
                              void* d_out, int out_size, void* d_ws, size_t ws_size,
                              hipStream_t stream)
{
    const float* x   = (const float*)d_in[0];
    const int*   c2v = (const int*)  d_in[1];
    const float* en  = (const float*)d_in[2];
    const float* ep  = (const float*)d_in[3];
    const float* Wt  = (const float*)d_in[4];
    const float* bt  = (const float*)d_in[5];
    const float* Wa  = (const float*)d_in[6];
    const float* ba  = (const float*)d_in[7];
    const float* Wsk = (const float*)d_in[8];
    const float* bsk = (const float*)d_in[9];
    const float* Wkc = (const float*)d_in[10];
    const float* bkc = (const float*)d_in[11];
    const float* Wpr = (const float*)d_in[12];
    const float* bpr = (const float*)d_in[13];

    float* out  = (float*)d_out;
    float* res  = out + OFF_RES;
    float* res2 = out + OFF_RES2;
    float* kcm  = out + OFF_KC;
    float* attn = out + OFF_ATTN;

    char* ws = (char*)d_ws;
    __bf16* wbt   = (__bf16*)ws;                                    // 225,280 B
    __bf16* enb   = (__bf16*)(ws + WBT_BYTES);                      // 4.0 MB
    __bf16* epb   = (__bf16*)(ws + WBT_BYTES + ENB_BYTES);          // 10.0 MB
    float*  es_ws = (float*)(ws + WBT_BYTES + ENB_BYTES + EPB_BYTES); // 41 MB

    const bool use_es = ws_size >= WS_NEED;

    // merged prep: wbt always; table conversion only on the ES path
    const int n_tab = use_es ? TAB_CHUNKS : 0;
    const int prep_ids = WBT_IDS + n_tab;
    prep_all_kernel<<<(prep_ids + 255) / 256, 256, 0, stream>>>(
        Wt, Wsk, en, ep, wbt, enb, epb, n_tab);

    if (use_es)
        score_mfma_kernel<true, true><<<NROWS / BM, TPB, 0, stream>>>(
            c2v, en, ep, enb, epb, wbt, bt, Wa, ba, attn, es_ws);
    else
        score_mfma_kernel<false, false><<<NROWS / BM, TPB, 0, stream>>>(
            c2v, en, ep, enb, epb, wbt, bt, Wa, ba, attn, es_ws);

    softmax_time_kernel<<<Bdim * Pdim, 64, 0, stream>>>(attn);

    if (use_es)
        cvpred6_kernel<<<(Bdim * Tdim) / BTPB, 512, 0, stream>>>(
            x, es_ws, attn, bsk, Wkc, bkc, Wpr, bpr, res, res2, kcm);
    else
        cvpred4_kernel<<<Bdim * Tdim, 512, 0, stream>>>(
            x, c2v, en, ep, attn, Wsk, bsk, Wkc, bkc, Wpr, bpr, res, res2, kcm);
}